// Round 16
// baseline (456.279 us; speedup 1.0000x reference)
//
#include <hip/hip_runtime.h>

// ---------------- constants ----------------
#define Bn 8
#define Sn 768
#define Hn 768
#define NHn 12
#define HDn 64
#define NLn 5

typedef unsigned short u16;
typedef __bf16 bf16x8 __attribute__((ext_vector_type(8)));
typedef short s16x8 __attribute__((ext_vector_type(8)));
typedef float f32x4 __attribute__((ext_vector_type(4)));
typedef unsigned short u16x4 __attribute__((ext_vector_type(4)));

static __device__ __forceinline__ float bf2f(u16 v) {
    return __uint_as_float(((unsigned)v) << 16);
}
static __device__ __forceinline__ u16 f2bf(float f) {
    unsigned u = __float_as_uint(f);
    unsigned r = u + 0x7fffu + ((u >> 16) & 1u);
    return (u16)(r >> 16);
}
static __device__ __forceinline__ bf16x8 ld8(const u16* p) {
    return *reinterpret_cast<const bf16x8*>(p);
}
static __device__ __forceinline__ void glds16(const u16* g, u16* l) {
    __builtin_amdgcn_global_load_lds(
        (const __attribute__((address_space(1))) void*)g,
        (__attribute__((address_space(3))) void*)l, 16, 0, 0);
}

// ---------------- fused prep: weight conversions + transposes ----------------
// f2b: ipw, projw (8 f32/thread).  transposes: Wq/Wk -> S, opw -> opwT.
#define PREP_NF2B 1152
#define PREP_NTR  (11 * 144)
__global__ __launch_bounds__(256) void k_prep(
    const float* __restrict__ ipw, u16* __restrict__ ipwb,
    const float* __restrict__ projw, u16* __restrict__ pjwb,
    const float* __restrict__ Wq, const float* __restrict__ Wk,
    const float* __restrict__ opw, u16* __restrict__ S, u16* __restrict__ opwT)
{
    __shared__ float T[64][65];
    const size_t HH = (size_t)Hn * Hn;
    const int bid = blockIdx.x, tid = threadIdx.x;
    if (bid < PREP_NF2B) {
        const int n1 = (int)(3 * HH / 8), n2 = (int)(HH / 8);
        int i = bid * 256 + tid;
        const float* s; u16* d; int off;
        if (i < n1)           { s = ipw;   d = ipwb; off = i; }
        else if (i < n1 + n2) { s = projw; d = pjwb; off = i - n1; }
        else return;
        float4 a = reinterpret_cast<const float4*>(s)[off * 2];
        float4 b = reinterpret_cast<const float4*>(s)[off * 2 + 1];
        s16x8 o;
        o[0] = (short)f2bf(a.x); o[1] = (short)f2bf(a.y);
        o[2] = (short)f2bf(a.z); o[3] = (short)f2bf(a.w);
        o[4] = (short)f2bf(b.x); o[5] = (short)f2bf(b.y);
        o[6] = (short)f2bf(b.z); o[7] = (short)f2bf(b.w);
        reinterpret_cast<s16x8*>(d)[off] = o;
    } else if (bid < PREP_NF2B + PREP_NTR) {
        int b2 = bid - PREP_NF2B;
        int z = b2 / 144, r = b2 % 144;
        int bx = r % 12, by = r / 12;
        const float* src;
        u16* dst;
        if (z < 5)       { src = Wq + (size_t)z * HH;        dst = S + (size_t)z * HH; }
        else if (z < 10) { src = Wk + (size_t)(z - 5) * HH;  dst = S + (size_t)z * HH; }
        else             { src = opw;                         dst = opwT; }
        int i0 = bx * 64, o0 = by * 64;
        #pragma unroll
        for (int it = 0; it < 4; ++it) {
            int s = tid + 256 * it;
            int row = s >> 4, seg = s & 15;
            float4 v = *reinterpret_cast<const float4*>(
                src + (size_t)(o0 + row) * Hn + i0 + seg * 4);
            T[row][seg * 4 + 0] = v.x;
            T[row][seg * 4 + 1] = v.y;
            T[row][seg * 4 + 2] = v.z;
            T[row][seg * 4 + 3] = v.w;
        }
        __syncthreads();
        #pragma unroll
        for (int it = 0; it < 2; ++it) {
            int s = tid + 256 * it;
            int ri = s >> 3, c8 = s & 7;
            s16x8 o;
            #pragma unroll
            for (int e = 0; e < 8; ++e)
                o[e] = (short)f2bf(T[c8 * 8 + e][ri]);
            *reinterpret_cast<s16x8*>(dst + (size_t)(i0 + ri) * Hn + o0 + c8 * 8) = o;
        }
    }
}

// ---- TM x 128 triple-buffered counted-vmcnt NT GEMM core (256 thr) ----
template<int TM>
__device__ __forceinline__ void gemm_core(
    const u16* __restrict__ A, int lda,
    const u16* __restrict__ Bw, int ldb,
    const float* __restrict__ bias,
    const float* __restrict__ addres,
    u16* __restrict__ outH, float* __restrict__ outF,
    u16* __restrict__ outVT, int ldc,
    int m0, int n0, float scale)
{
    constexpr int MI = TM / 32;
    constexpr int AIT = TM / 64;
    __shared__ u16 As[3 * TM * 32];
    __shared__ u16 Bs[3 * 128 * 32];
    const int tid = threadIdx.x;
    const int lane = tid & 63, wave = tid >> 6;
    const int lrow = lane & 15, lquad = lane >> 4;
    const int wm = (wave >> 1) * (TM / 2), wn = (wave & 1) * 64;

    const u16* gA = A + (size_t)(m0 + (tid >> 2)) * lda + (tid & 3) * 8;
    const u16* gB = Bw + (size_t)(n0 + (tid >> 2)) * ldb + (tid & 3) * 8;

    f32x4 z = {0.f, 0.f, 0.f, 0.f};
    f32x4 acc[MI][4];
    #pragma unroll
    for (int i = 0; i < MI; ++i)
        #pragma unroll
        for (int j = 0; j < 4; ++j) acc[i][j] = z;

    auto stage = [&](int bs, int k0) {
        #pragma unroll
        for (int it = 0; it < AIT; ++it)
            glds16(gA + (size_t)(it * 64) * lda + k0, &As[bs * TM * 32 + (tid + 256 * it) * 8]);
        #pragma unroll
        for (int it = 0; it < 2; ++it)
            glds16(gB + (size_t)(it * 64) * ldb + k0, &Bs[bs * 128 * 32 + (tid + 256 * it) * 8]);
    };
    auto compute = [&](int bc) {
        const u16* Ab = &As[bc * TM * 32];
        const u16* Bb = &Bs[bc * 128 * 32];
        bf16x8 af[MI], bf_[4];
        #pragma unroll
        for (int i = 0; i < MI; ++i)
            af[i] = ld8(&Ab[(wm + i * 16 + lrow) * 32 + lquad * 8]);
        #pragma unroll
        for (int j = 0; j < 4; ++j)
            bf_[j] = ld8(&Bb[(wn + j * 16 + lrow) * 32 + lquad * 8]);
        #pragma unroll
        for (int i = 0; i < MI; ++i)
            #pragma unroll
            for (int j = 0; j < 4; ++j)
                acc[i][j] = __builtin_amdgcn_mfma_f32_16x16x32_bf16(af[i], bf_[j], acc[i][j], 0, 0, 0);
    };

    stage(0, 0);
    stage(1, 32);
    int bc = 0, bs = 2;
    for (int kt = 0; kt < 24; ++kt) {
        if (kt < 23) {
            if constexpr (TM == 256) {
                asm volatile("s_waitcnt vmcnt(6)" ::: "memory");
            } else {
                asm volatile("s_waitcnt vmcnt(4)" ::: "memory");
            }
        } else {
            asm volatile("s_waitcnt vmcnt(0)" ::: "memory");
        }
        __builtin_amdgcn_s_barrier();
        if (kt < 22) {
            stage(bs, (kt + 2) * 32);
            bs = (bs == 2) ? 0 : bs + 1;
        }
        compute(bc);
        bc = (bc == 2) ? 0 : bc + 1;
    }

    #pragma unroll
    for (int i = 0; i < MI; ++i) {
        #pragma unroll
        for (int j = 0; j < 4; ++j) {
            int col = n0 + wn + j * 16 + lrow;
            float bv = bias ? bias[col] : 0.f;
            if (outVT) {
                int row0 = m0 + wm + i * 16 + lquad * 4;
                int bb = row0 / Sn, s = row0 % Sn;
                int hh = col >> 6, dd = col & 63;
                u16x4 o;
                #pragma unroll
                for (int r = 0; r < 4; ++r) o[r] = f2bf((acc[i][j][r] + bv) * scale);
                *reinterpret_cast<u16x4*>(
                    outVT + (((size_t)bb * NHn + hh) * 64 + dd) * Sn + s) = o;
            } else {
                #pragma unroll
                for (int r = 0; r < 4; ++r) {
                    int row = m0 + wm + i * 16 + lquad * 4 + r;
                    float v = (acc[i][j][r] + bv) * scale;
                    if (addres) v += addres[(size_t)row * ldc + col];
                    if (outF) outF[(size_t)row * ldc + col] = v;
                    else      outH[(size_t)row * ldc + col] = f2bf(v);
                }
            }
        }
    }
}

// -- 64x64 triple-buffered counted-vmcnt NT GEMM core (256 thr), LDS passed in --
__device__ __forceinline__ void gemm64(
    u16* As, u16* Bs,
    const u16* __restrict__ A, const u16* __restrict__ Bw,
    const float* __restrict__ bias, const float* __restrict__ addres,
    u16* __restrict__ outH, float* __restrict__ outF,
    int m0, int n0)
{
    const int tid = threadIdx.x;
    const int lane = tid & 63, wave = tid >> 6;
    const int lrow = lane & 15, lquad = lane >> 4;
    const int wm = (wave >> 1) * 32, wn = (wave & 1) * 32;

    const u16* gA = A + (size_t)(m0 + (tid >> 2)) * Hn + (tid & 3) * 8;
    const u16* gB = Bw + (size_t)(n0 + (tid >> 2)) * Hn + (tid & 3) * 8;

    f32x4 z = {0.f, 0.f, 0.f, 0.f};
    f32x4 acc[2][2];
    #pragma unroll
    for (int i = 0; i < 2; ++i)
        #pragma unroll
        for (int j = 0; j < 2; ++j) acc[i][j] = z;

    auto stage = [&](int bs, int k0) {
        glds16(gA + k0, &As[bs * 64 * 32 + tid * 8]);
        glds16(gB + k0, &Bs[bs * 64 * 32 + tid * 8]);
    };
    auto compute = [&](int bc) {
        const u16* Ab = &As[bc * 64 * 32];
        const u16* Bb = &Bs[bc * 64 * 32];
        bf16x8 af[2], bf_[2];
        #pragma unroll
        for (int i = 0; i < 2; ++i)
            af[i] = ld8(&Ab[(wm + i * 16 + lrow) * 32 + lquad * 8]);
        #pragma unroll
        for (int j = 0; j < 2; ++j)
            bf_[j] = ld8(&Bb[(wn + j * 16 + lrow) * 32 + lquad * 8]);
        #pragma unroll
        for (int i = 0; i < 2; ++i)
            #pragma unroll
            for (int j = 0; j < 2; ++j)
                acc[i][j] = __builtin_amdgcn_mfma_f32_16x16x32_bf16(af[i], bf_[j], acc[i][j], 0, 0, 0);
    };

    stage(0, 0);
    stage(1, 32);
    int bc = 0, bs = 2;
    for (int kt = 0; kt < 24; ++kt) {
        if (kt < 23) {
            asm volatile("s_waitcnt vmcnt(2)" ::: "memory");
        } else {
            asm volatile("s_waitcnt vmcnt(0)" ::: "memory");
        }
        __builtin_amdgcn_s_barrier();
        if (kt < 22) {
            stage(bs, (kt + 2) * 32);
            bs = (bs == 2) ? 0 : bs + 1;
        }
        compute(bc);
        bc = (bc == 2) ? 0 : bc + 1;
    }

    #pragma unroll
    for (int i = 0; i < 2; ++i)
        #pragma unroll
        for (int j = 0; j < 2; ++j) {
            int col = n0 + wn + j * 16 + lrow;
            float bv = bias ? bias[col] : 0.f;
            #pragma unroll
            for (int r = 0; r < 4; ++r) {
                int row_ = m0 + wm + i * 16 + lquad * 4 + r;
                float v = acc[i][j][r] + bv;
                if (addres) v += addres[(size_t)row_ * Hn + col];
                if (outF) outF[(size_t)row_ * Hn + col] = v;
                else      outH[(size_t)row_ * Hn + col] = f2bf(v);
            }
        }
}

// ---- 64x64 tile helpers (256 thr): identity write, copy, transposing copy ----
static __device__ __forceinline__ void ident64(u16* dst, int m0, int n0)
{
    const int tid = threadIdx.x;
    #pragma unroll
    for (int it = 0; it < 2; ++it) {
        int s = tid + 256 * it;
        int ri = s >> 3, c8 = s & 7;
        s16x8 v;
        #pragma unroll
        for (int e = 0; e < 8; ++e)
            v[e] = (short)((m0 + ri == n0 + c8 * 8 + e) ? 0x3F80 : 0);
        *reinterpret_cast<s16x8*>(dst + (size_t)(m0 + ri) * Hn + n0 + c8 * 8) = v;
    }
}
static __device__ __forceinline__ void copy64(u16* dst, const u16* src, int m0, int n0)
{
    const int tid = threadIdx.x;
    #pragma unroll
    for (int it = 0; it < 2; ++it) {
        int s = tid + 256 * it;
        int row = s >> 3, seg = s & 7;
        *reinterpret_cast<s16x8*>(dst + (size_t)(m0 + row) * Hn + n0 + seg * 8) =
            *reinterpret_cast<const s16x8*>(src + (size_t)(m0 + row) * Hn + n0 + seg * 8);
    }
}
// dst = src^T: dst tile (m0,n0) <- src tile (n0,m0) transposed.  lds >= 64*72 u16
static __device__ __forceinline__ void tcopy64(u16* dst, const u16* src, int m0, int n0, u16* lds)
{
    u16 (*T)[72] = reinterpret_cast<u16(*)[72]>(lds);
    const int tid = threadIdx.x;
    #pragma unroll
    for (int it = 0; it < 2; ++it) {
        int s = tid + 256 * it;
        int rr = s >> 3, c8 = s & 7;
        s16x8 v = *reinterpret_cast<const s16x8*>(
            src + (size_t)(n0 + rr) * Hn + m0 + c8 * 8);
        #pragma unroll
        for (int e = 0; e < 8; ++e) T[c8 * 8 + e][rr] = (u16)v[e];
    }
    __syncthreads();
    #pragma unroll
    for (int it = 0; it < 2; ++it) {
        int s = tid + 256 * it;
        int ri = s >> 3, c8 = s & 7;
        *reinterpret_cast<s16x8*>(dst + (size_t)(m0 + ri) * Hn + n0 + c8 * 8) =
            *reinterpret_cast<const s16x8*>(&T[ri][c8 * 8]);
    }
}

// ---------------- GEMM wrapper kernels ----------------

// comb + aux backfill.  flat grid 3774 blocks, LONG-LATENCY WORK FIRST:
//   [0, 30): combined QK bias GEMVs (serial 768-dot per thread)
//   [30, 1470): Weffq/Weffk 64^2 tiles
//   [1470, 3774): hidden f32 -> bf16 (8 f32/thread)
__global__ __launch_bounds__(256) void k_comb_aux(
    const u16* __restrict__ ipwb, u16* __restrict__ S,
    const float* __restrict__ hidden, u16* __restrict__ hb,
    const float* __restrict__ ipw, const float* __restrict__ ipb,
    const float* __restrict__ bq_lang, const float* __restrict__ bk_lang,
    float* __restrict__ beff)
{
    __shared__ u16 As[3 * 64 * 32];
    __shared__ u16 Bs[3 * 64 * 32];
    const size_t HH = (size_t)Hn * Hn;
    const int bid = blockIdx.x, tid = threadIdx.x;
    if (bid < 30) {
        int ox = bid % 3, y = bid / 3;
        int o = ox * 256 + tid;
        int which = y / 5, l = y % 5;
        const float4* w = reinterpret_cast<const float4*>(ipw + (size_t)which * HH + (size_t)o * Hn);
        const float4* bv = reinterpret_cast<const float4*>(((which ? bk_lang : bq_lang) + (size_t)l * Hn));
        float s = 0.f;
        for (int j = 0; j < Hn / 4; ++j) {
            float4 a = w[j], b = bv[j];
            s += a.x * b.x + a.y * b.y + a.z * b.z + a.w * b.w;
        }
        s += ipb[which * Hn + o];
        beff[(size_t)(which * 5 + l) * Hn + o] = s;
    } else if (bid < 1470) {
        int b2 = bid - 30;
        int z = b2 / 144, r = b2 % 144;
        const u16* Aop = ipwb + (z < 5 ? 0 : HH);
        gemm64(As, Bs, Aop, S + (size_t)z * HH, nullptr, nullptr,
               S + (size_t)(10 + z) * HH, nullptr,
               (r % 12) * 64, (r / 12) * 64);
    } else {
        int i = (bid - 1470) * 256 + tid;          // 589824 threads
        float4 a = reinterpret_cast<const float4*>(hidden)[i * 2];
        float4 b = reinterpret_cast<const float4*>(hidden)[i * 2 + 1];
        s16x8 o;
        o[0] = (short)f2bf(a.x); o[1] = (short)f2bf(a.y);
        o[2] = (short)f2bf(a.z); o[3] = (short)f2bf(a.w);
        o[4] = (short)f2bf(b.x); o[5] = (short)f2bf(b.y);
        o[6] = (short)f2bf(b.z); o[7] = (short)f2bf(b.w);
        reinterpret_cast<s16x8*>(hb)[i] = o;
    }
}

// fused QKV projection, 256-row tiles (432 blocks -> ONE generation at 2/CU).
__global__ __launch_bounds__(256, 2) void k_gemm_qkv(
    const u16* __restrict__ A,
    const u16* __restrict__ Sq, const u16* __restrict__ Sk,
    const u16* __restrict__ Wv,
    const float* __restrict__ beff, const float* __restrict__ ipb,
    const int* __restrict__ lang,
    u16* __restrict__ outQ, u16* __restrict__ outK, u16* __restrict__ outVT)
{
    const size_t HH = (size_t)Hn * Hn;
    int z = blockIdx.z;
    int m0 = blockIdx.x * 256, n0 = blockIdx.y * 128;
    int l = lang[blockIdx.x / 3];
    if (z == 0) {
        gemm_core<256>(A, Hn, Sq + (size_t)l * HH, Hn, beff + (size_t)l * Hn,
                       nullptr, outQ, nullptr, nullptr, Hn, m0, n0, 0.125f);
    } else if (z == 1) {
        gemm_core<256>(A, Hn, Sk + (size_t)l * HH, Hn, beff + (size_t)(5 + l) * Hn,
                       nullptr, outK, nullptr, nullptr, Hn, m0, n0, 1.f);
    } else {
        gemm_core<256>(A, Hn, Wv, Hn, ipb + 2 * Hn,
                       nullptr, nullptr, nullptr, outVT, Hn, m0, n0, 1.f);
    }
}

// ---------------- chain tree ----------------
// MT_l = S7^T S6^T ... S0^T;  S_j = (lang[j]==l) ? I : align[l, lang[j]].

// L1.  grid (12,12,20)
__global__ __launch_bounds__(256) void k_chainL1(
    const u16* __restrict__ alignb, const u16* __restrict__ alignbT,
    const int* __restrict__ lang, u16* __restrict__ N1)
{
    __shared__ u16 As[3 * 64 * 32];
    __shared__ u16 Bs[3 * 64 * 32];
    const size_t HH = (size_t)Hn * Hn;
    int idx = blockIdx.z, l = idx >> 2, node = idx & 3;
    int ja = 7 - node * 2, jb = 6 - node * 2;
    bool tr = node & 1;
    int la = lang[ja], lb = lang[jb];
    bool sa = (la == l), sb = (lb == l);
    u16* dst = N1 + (size_t)idx * HH;
    int m0 = blockIdx.x * 64, n0 = blockIdx.y * 64;
    if (sa && sb) {
        ident64(dst, m0, n0);
    } else if (sa) {
        copy64(dst, (tr ? alignb : alignbT) + ((size_t)l * NLn + lb) * HH, m0, n0);
    } else if (sb) {
        copy64(dst, (tr ? alignb : alignbT) + ((size_t)l * NLn + la) * HH, m0, n0);
    } else if (!tr) {  // straight: Fa^T * Fb^T = NT(FaT, Fb)
        gemm64(As, Bs, alignbT + ((size_t)l * NLn + la) * HH,
               alignb + ((size_t)l * NLn + lb) * HH,
               nullptr, nullptr, dst, nullptr, m0, n0);
    } else {           // transposed: Fb * Fa = NT(Fb, FaT)
        gemm64(As, Bs, alignb + ((size_t)l * NLn + lb) * HH,
               alignbT + ((size_t)l * NLn + la) * HH,
               nullptr, nullptr, dst, nullptr, m0, n0);
    }
}

// L2.  grid (12,12,10): z = l*2 + q.  Q_a -> Q2[l], Q_bT -> Q2[5+l]
__global__ __launch_bounds__(256) void k_chainL2(
    const u16* __restrict__ N1, const int* __restrict__ lang,
    u16* __restrict__ Q2)
{
    __shared__ u16 As[3 * 64 * 32];
    __shared__ u16 Bs[3 * 64 * 32];
    const size_t HH = (size_t)Hn * Hn;
    int idx = blockIdx.z, l = idx >> 1, q = idx & 1;
    int m0 = blockIdx.x * 64, n0 = blockIdx.y * 64;
    const u16* Pa  = N1 + (size_t)(l * 4 + 0) * HH;
    const u16* PbT = N1 + (size_t)(l * 4 + 1) * HH;
    const u16* Pc  = N1 + (size_t)(l * 4 + 2) * HH;
    const u16* PdT = N1 + (size_t)(l * 4 + 3) * HH;
    if (q == 0) {
        u16* dst = Q2 + (size_t)l * HH;
        bool ia = (lang[7] == l) && (lang[6] == l);
        bool ib = (lang[5] == l) && (lang[4] == l);
        if (ia && ib)      ident64(dst, m0, n0);
        else if (ia)       tcopy64(dst, PbT, m0, n0, As);
        else if (ib)       copy64(dst, Pa, m0, n0);
        else               gemm64(As, Bs, Pa, PbT, nullptr, nullptr, dst, nullptr, m0, n0);
    } else {
        u16* dst = Q2 + (size_t)(5 + l) * HH;
        bool ic = (lang[3] == l) && (lang[2] == l);
        bool id = (lang[1] == l) && (lang[0] == l);
        if (ic && id)      ident64(dst, m0, n0);
        else if (ic)       copy64(dst, PdT, m0, n0);
        else if (id)       tcopy64(dst, Pc, m0, n0, As);
        else               gemm64(As, Bs, PdT, Pc, nullptr, nullptr, dst, nullptr, m0, n0);
    }
}

// L3.  grid (12,12,5): MT_l = Q_a * Q_b = NT(Q_a, Q_bT)
__global__ __launch_bounds__(256) void k_chainL3(
    const u16* __restrict__ Q2, const int* __restrict__ lang,
    u16* __restrict__ MT)
{
    __shared__ u16 As[3 * 64 * 32];
    __shared__ u16 Bs[3 * 64 * 32];
    const size_t HH = (size_t)Hn * Hn;
    int l = blockIdx.z;
    int m0 = blockIdx.x * 64, n0 = blockIdx.y * 64;
    const u16* Qa  = Q2 + (size_t)l * HH;
    const u16* QbT = Q2 + (size_t)(5 + l) * HH;
    u16* dst = MT + (size_t)l * HH;
    bool iA = (lang[7] == l) && (lang[6] == l) && (lang[5] == l) && (lang[4] == l);
    bool iB = (lang[3] == l) && (lang[2] == l) && (lang[1] == l) && (lang[0] == l);
    if (iA && iB)      ident64(dst, m0, n0);
    else if (iA)       tcopy64(dst, QbT, m0, n0, As);
    else if (iB)       copy64(dst, Qa, m0, n0);
    else               gemm64(As, Bs, Qa, QbT, nullptr, nullptr, dst, nullptr, m0, n0);
}

// U_l = NT(opwT, MT_l) + opb_eff GEMV.  grid 735, GEMVs FIRST.
__global__ __launch_bounds__(256) void k_uop(
    const u16* __restrict__ opwT, const u16* __restrict__ MT,
    const float* __restrict__ opb,
    u16* __restrict__ U5, float* __restrict__ opbeff)
{
    __shared__ u16 As[3 * 64 * 32];
    __shared__ u16 Bs[3 * 64 * 32];
    const size_t HH = (size_t)Hn * Hn;
    int bid = blockIdx.x;
    if (bid < 15) {
        int n = (bid % 3) * 256 + threadIdx.x;
        int l = bid / 3;
        const u16* mt = MT + ((size_t)l * Hn + n) * Hn;
        float s = 0.f;
        for (int k = 0; k < Hn; k += 8) {
            s16x8 v = *reinterpret_cast<const s16x8*>(mt + k);
            #pragma unroll
            for (int jq = 0; jq < 8; ++jq) s += opb[k + jq] * bf2f((u16)v[jq]);
        }
        opbeff[(size_t)l * Hn + n] = s;
    } else {
        int b2 = bid - 15;
        int z = b2 / 144, r = b2 % 144;
        gemm64(As, Bs, opwT, MT + (size_t)z * HH, nullptr, nullptr,
               U5 + (size_t)z * HH, nullptr,
               (r % 12) * 64, (r / 12) * 64);
    }
}

// W_l = NT(projw, U_l) + bias2 GEMV.  grid 735, GEMVs FIRST.
__global__ __launch_bounds__(256) void k_wb2(
    const u16* __restrict__ pjwb, const u16* __restrict__ U5,
    const float* __restrict__ opbeff, const float* __restrict__ projw,
    const float* __restrict__ projb,
    u16* __restrict__ W5, float* __restrict__ bias2)
{
    __shared__ u16 As[3 * 64 * 32];
    __shared__ u16 Bs[3 * 64 * 32];
    const size_t HH = (size_t)Hn * Hn;
    int bid = blockIdx.x;
    if (bid < 15) {
        int m = (bid % 3) * 256 + threadIdx.x;
        int l = bid / 3;
        const float4* w = reinterpret_cast<const float4*>(projw + (size_t)m * Hn);
        const float4* ob = reinterpret_cast<const float4*>(opbeff + (size_t)l * Hn);
        float s = 0.f;
        for (int jq = 0; jq < Hn / 4; ++jq) {
            float4 a = w[jq], b = ob[jq];
            s += a.x * b.x + a.y * b.y + a.z * b.z + a.w * b.w;
        }
        bias2[(size_t)l * Hn + m] = s + projb[m];
    } else {
        int b2 = bid - 15;
        int z = b2 / 144, r = b2 % 144;
        gemm64(As, Bs, pjwb, U5 + (size_t)z * HH, nullptr, nullptr,
               W5 + (size_t)z * HH, nullptr,
               (r % 12) * 64, (r / 12) * 64);
    }
}

// x = NT(ctx, W[lang]) + bias2[lang] + hidden -> f32 out.  128^2 tiles, grid (48,6)
__global__ __launch_bounds__(256) void k_xfused(
    const u16* __restrict__ ctx, const u16* __restrict__ W5,
    const float* __restrict__ bias2, const int* __restrict__ lang,
    const float* __restrict__ hidden, float* __restrict__ x)
{
    int l = lang[blockIdx.x / 6];
    gemm_core<128>(ctx, Hn, W5 + (size_t)l * Hn * Hn, Hn, bias2 + (size_t)l * Hn,
                   hidden, nullptr, x, nullptr, Hn,
                   blockIdx.x * 128, blockIdx.y * 128, 1.f);
}

// ---------------- flash attention + align conversion, 512 threads ----------
// blocks [0,576): attn.  blocks [576, 1476): align conversion, 4 tiles per
// block (deep grid-stride) — stage f32 tile ONCE, write alignb + alignbT.
__global__ __launch_bounds__(512) void k_attn_conv(
    const u16* __restrict__ Q, const u16* __restrict__ K,
    const u16* __restrict__ VT, u16* __restrict__ ctx,
    const float* __restrict__ alignf, u16* __restrict__ alignb,
    u16* __restrict__ alignbT)
{
    __shared__ u16 Ks[2][64 * 64];       // [key][d], seg-xor-swizzled
    __shared__ u16 Vs[2][64 * 64];       // [d][key], seg-xor-swizzled
    __shared__ u16 Pw[8][16 * 72];       // per-wave P; conv: f32 T[64][65]

    const int bid = blockIdx.x, tid = threadIdx.x;
    const size_t HH = (size_t)Hn * Hn;
    if (bid >= 576) {
        float (*T)[65] = reinterpret_cast<float(*)[65]>(&Pw[0][0]);
        const int row = tid >> 3, c8 = tid & 7;
        #pragma unroll
        for (int tt = 0; tt < 4; ++tt) {
            int t = (bid - 576) * 4 + tt;        // 0..3599
            int mat = t / 144, r = t % 144;
            int i0 = (r % 12) * 64, o0 = (r / 12) * 64;
            const float* src = alignf + (size_t)mat * HH;
            const float* p = src + (size_t)(o0 + row) * Hn + i0 + c8 * 8;
            float4 a = *reinterpret_cast<const float4*>(p);
            float4 b = *reinterpret_cast<const float4*>(p + 4);
            s16x8 o;
            o[0] = (short)f2bf(a.x); o[1] = (short)f2bf(a.y);
            o[2] = (short)f2bf(a.z); o[3] = (short)f2bf(a.w);
            o[4] = (short)f2bf(b.x); o[5] = (short)f2bf(b.y);
            o[6] = (short)f2bf(b.z); o[7] = (short)f2bf(b.w);
            *reinterpret_cast<s16x8*>(
                alignb + (size_t)mat * HH + (size_t)(o0 + row) * Hn + i0 + c8 * 8) = o;
            T[row][c8 * 8 + 0] = a.x; T[row][c8 * 8 + 1] = a.y;
            T[row][c8 * 8 + 2] = a.z; T[row][c8 * 8 + 3] = a.w;
            T[row][c8 * 8 + 4] = b.x; T[row][c8 * 8 + 5] = b.y;
            T[row][c8 * 8 + 6] = b.z; T[row][c8 * 8 + 7] = b.w;
            __syncthreads();
            s16x8 ot;
            #pragma unroll
            for (int e = 0; e < 8; ++e)
                ot[e] = (short)f2bf(T[c8 * 8 + e][row]);
            *reinterpret_cast<s16x8*>(
                alignbT + (size_t)mat * HH + (size_t)(i0 + row) * Hn + o0 + c8 * 8) = ot;
            __syncthreads();                     // LDS reuse guard
        }
        return;
    }

    const int q0 = (bid % 6) * 128, h = (bid / 6) % NHn, bz = bid / 72;
    const int wave = tid >> 6, lane = tid & 63;
    const int lrow = lane & 15, lquad = lane >> 4;
    const int sw = lrow & 7;

    const u16* Qp = Q + ((size_t)(bz * Sn + q0 + wave * 16 + lrow)) * Hn + h * HDn;
    const u16* Kb = K + (size_t)bz * Sn * Hn + h * HDn;
    const u16* Vb = VT + ((size_t)(bz * NHn + h) * 64) * Sn;   // row d, stride Sn

    bf16x8 qa0 = ld8(Qp + lquad * 8);
    bf16x8 qa1 = ld8(Qp + 32 + lquad * 8);

    f32x4 z4 = {0.f, 0.f, 0.f, 0.f};
    float m_r[4], l_l[4];
    f32x4 oacc[4];
    #pragma unroll
    for (int r = 0; r < 4; ++r) { m_r[r] = -1e30f; l_l[r] = 0.f; }
    #pragma unroll
    for (int jd = 0; jd < 4; ++jd) oacc[jd] = z4;

    const int krow = tid >> 3, kp = (tid & 7) ^ (krow & 7);
    const u16* kg = Kb + (size_t)krow * Hn + kp * 8;
    const u16* vg = Vb + (size_t)krow * Sn + kp * 8;

    auto stage = [&](int bs, int t0) {
        glds16(kg + (size_t)t0 * Hn, &Ks[bs][tid * 8]);
        glds16(vg + t0, &Vs[bs][tid * 8]);
    };

    auto compute = [&](int bc) {
        f32x4 sc[4];
        __builtin_amdgcn_s_setprio(1);
        #pragma unroll
        for (int j = 0; j < 4; ++j) {
            int base = (j * 16 + lrow) * 64 + ((lquad ^ sw) * 8);
            f32x4 s = __builtin_amdgcn_mfma_f32_16x16x32_bf16(qa0, ld8(&Ks[bc][base]), z4, 0, 0, 0);
            sc[j] = __builtin_amdgcn_mfma_f32_16x16x32_bf16(qa1, ld8(&Ks[bc][base ^ 32]), s, 0, 0, 0);
        }
        __builtin_amdgcn_s_setprio(0);
        float tmax[4];
        #pragma unroll
        for (int r = 0; r < 4; ++r)
            tmax[r] = fmaxf(fmaxf(sc[0][r], sc[1][r]), fmaxf(sc[2][r], sc[3][r]));
        #pragma unroll
        for (int off = 1; off < 16; off <<= 1)
            #pragma unroll
            for (int r = 0; r < 4; ++r)
                tmax[r] = fmaxf(tmax[r], __shfl_xor(tmax[r], off));
        bool grow = (tmax[0] > m_r[0] + 8.f) | (tmax[1] > m_r[1] + 8.f) |
                    (tmax[2] > m_r[2] + 8.f) | (tmax[3] > m_r[3] + 8.f);
        if (grow) {
            #pragma unroll
            for (int r = 0; r < 4; ++r) {
                float mn = fmaxf(m_r[r], tmax[r]);
                float a = __expf(m_r[r] - mn);
                m_r[r] = mn;
                l_l[r] *= a;
                #pragma unroll
                for (int jd = 0; jd < 4; ++jd) oacc[jd][r] *= a;
            }
        }
        float ps[4] = {0.f, 0.f, 0.f, 0.f};
        #pragma unroll
        for (int j = 0; j < 4; ++j)
            #pragma unroll
            for (int r = 0; r < 4; ++r) {
                float p = __expf(sc[j][r] - m_r[r]);
                ps[r] += p;
                Pw[wave][(lquad * 4 + r) * 72 + j * 16 + lrow] = f2bf(p);
            }
        #pragma unroll
        for (int r = 0; r < 4; ++r) l_l[r] += ps[r];
        bf16x8 pa0 = ld8(&Pw[wave][lrow * 72 + lquad * 8]);
        bf16x8 pa1 = ld8(&Pw[wave][lrow * 72 + 32 + lquad * 8]);
        __builtin_amdgcn_s_setprio(1);
        #pragma unroll
        for (int jd = 0; jd < 4; ++jd) {
            int vbase = (jd * 16 + lrow) * 64 + ((lquad ^ sw) * 8);
            oacc[jd] = __builtin_amdgcn_mfma_f32_16x16x32_bf16(pa0, ld8(&Vs[bc][vbase]), oacc[jd], 0, 0, 0);
            oacc[jd] = __builtin_amdgcn_mfma_f32_16x16x32_bf16(pa1, ld8(&Vs[bc][vbase ^ 32]), oacc[jd], 0, 0, 0);
        }
        __builtin_amdgcn_s_setprio(0);
    };

    stage(0, 0);
    stage(1, 64);
    for (int kt = 0; kt < 12; ++kt) {
        if (kt < 11) {
            asm volatile("s_waitcnt vmcnt(2)" ::: "memory");
        } else {
            asm volatile("s_waitcnt vmcnt(0)" ::: "memory");
        }
        __builtin_amdgcn_s_barrier();
        compute(kt & 1);
        if (kt < 10) {
            __builtin_amdgcn_s_barrier();
            stage(kt & 1, (kt + 2) * 64);
        }
    }

    #pragma unroll
    for (int off = 1; off < 16; off <<= 1)
        #pragma unroll
        for (int r = 0; r < 4; ++r)
            l_l[r] += __shfl_xor(l_l[r], off);

    float rl[4];
    #pragma unroll
    for (int r = 0; r < 4; ++r) rl[r] = 1.f / l_l[r];
    #pragma unroll
    for (int jd = 0; jd < 4; ++jd)
        #pragma unroll
        for (int r = 0; r < 4; ++r) {
            size_t row = (size_t)bz * Sn + q0 + wave * 16 + lquad * 4 + r;
            ctx[row * Hn + h * HDn + jd * 16 + lrow] = f2bf(oacc[jd][r] * rl[r]);
        }
}

// layernorm in-place on f32 d_out.  256 thr = 4 waves, one row per wave.
// grid B*S/4 = 1536.
__global__ __launch_bounds__(256) void k_ln(
    float* x, const float* __restrict__ g, const float* __restrict__ beta)
{
    int wave = threadIdx.x >> 6, lane = threadIdx.x & 63;
    size_t row = (size_t)blockIdx.x * 4 + wave;
    float* xr = x + row * Hn;
    float v[12];
    float s = 0.f, ss = 0.f;
    #pragma unroll
    for (int i = 0; i < 12; ++i) {
        v[i] = xr[lane + i * 64];
        s += v[i];
        ss += v[i] * v[i];
    }
    #pragma unroll
    for (int off = 1; off < 64; off <<= 1) {
        s  += __shfl_xor(s, off);
        ss += __shfl_xor(ss, off);
    }
    float mu = s * (1.f / Hn);
    float var = ss * (1.f / Hn) - mu * mu;
    float inv = rsqrtf(var + 1e-5f);
    #pragma unroll
    for (int i = 0; i < 12; ++i) {
        int c = lane + i * 64;
        xr[c] = (v[i] - mu) * inv * g[c] + beta[c];
    }
}

// ---------------- launch ----------------
extern "C" void kernel_launch(void* const* d_in, const int* in_sizes, int n_in,
                              void* d_out, int out_size, void* d_ws, size_t ws_size,
                              hipStream_t stream)
{
    (void)in_sizes; (void)n_in; (void)out_size; (void)ws_size;

    const float* hidden  = (const float*)d_in[0];
    const int*   lang    = (const int*)d_in[1];
    const float* Wq_lang = (const float*)d_in[3];
    const float* bq_lang = (const float*)d_in[4];
    const float* Wk_lang = (const float*)d_in[5];
    const float* bk_lang = (const float*)d_in[6];
    const float* ipw     = (const float*)d_in[7];
    const float* ipb     = (const float*)d_in[8];
    const float* opw     = (const float*)d_in[9];
    const float* opb     = (const float*)d_in[10];
    const float* align   = (const float*)d_in[11];
    const float* projw   = (const float*)d_in[12];
    const float* projb   = (const float*)d_in[13];
    const float* ln_g    = (const float*)d_in[14];
    const float* ln_b    = (const float*)d_in[15];
    float* out = (float*)d_out;

    const size_t HH  = (size_t)Hn * Hn;          // 589824
    const size_t BSH = (size_t)Bn * Sn * Hn;     // 4718592 = 8*HH
    const size_t AHH = (size_t)NLn * NLn * HH;   // 25*HH

    u16* rA = (u16*)d_ws;        // hb -> ctx
    u16* rB = rA + BSH;          // Q -> N1 slots 0..7
    u16* rC = rB + BSH;          // K -> N1 slots 8..15
    u16* rD = rC + BSH;          // V^T -> N1 slots 16..19
    u16* ipwb = rD + BSH;        // wq|wk|wv bf16 (3*HH)
    u16* pjwb = ipwb + 3 * HH;   // HH
    u16* opwT = pjwb + HH;       // HH
    u16* alignb = opwT + HH;     // 25*HH; pre-attn: weight scratch S[0..20)
                                 // post-L2: MT[0..5) U[5..10) W[10..15)
    u16* alignbT = alignb + AHH; // 25*HH transposed aligns (written by attn_conv);
                                 // post-L1: Q2[0..10)
    float* beff   = (float*)(alignbT + AHH);  // 2*5*768 f32
    float* opbeff = beff + 10 * Hn;           // 5*768 f32
    float* bias2  = opbeff + 5 * Hn;          // 5*768 f32

    u16* S = alignb;             // scratch: WqT[0..5) WkT[5..10) Weffq[10..15) Weffk[15..20)
    u16* N1 = rB;                // 20 node matrices (rB..rD contiguous)
    u16* Q2 = alignbT;           // 10 node matrices (alignbT dead after L1)
    u16* MT = alignb;            // 5 (alignb dead after L1)
    u16* U5 = alignb + 5 * HH;   // 5
    u16* W5 = alignb + 10 * HH;  // 5

    // prep: weight conversions + 11 transposes (Wq/Wk/opw)
    k_prep<<<(unsigned)(PREP_NF2B + PREP_NTR), 256, 0, stream>>>(
        ipw, ipwb, projw, pjwb, Wq_lang, Wk_lang, opw, S, opwT);

    // biasqk (front) + Weffq/Weffk GEMMs + hidden f32->bf16 backfill (one launch)
    k_comb_aux<<<3774, 256, 0, stream>>>(
        ipwb, S, hidden, rA, ipw, ipb, bq_lang, bk_lang, beff);

    // fused QKV: Q*(1/8) -> rB, K -> rC, V^T -> rD.  256-row tiles, 1 generation.
    k_gemm_qkv<<<dim3(24, 6, 3), 256, 0, stream>>>(
        rA, S + 10 * HH, S + 15 * HH, ipwb + 2 * HH, beff, ipb, lang, rB, rC, rD);

    // attention (ctx -> rA) + align f32 staged ONCE -> alignb + alignbT
    // (S scratch dead once qkv completes); conv tail 900 deep blocks x 4 tiles
    k_attn_conv<<<1476, 512, 0, stream>>>(rB, rC, rD, rA, align, alignb, alignbT);

    // chain tree: 3 launches replace 8 sequential chain steps
    k_chainL1<<<dim3(12, 12, 20), 256, 0, stream>>>(alignb, alignbT, lang, N1);
    k_chainL2<<<dim3(12, 12, 10), 256, 0, stream>>>(N1, lang, Q2);
    k_chainL3<<<dim3(12, 12, 5), 256, 0, stream>>>(Q2, lang, MT);

    // U_l = opw^T . M_l  (GEMV first, then tiles)
    k_uop<<<735, 256, 0, stream>>>(opwT, MT, opb, U5, opbeff);
    // W_l = projw . U_l  (GEMV first, then tiles)
    k_wb2<<<735, 256, 0, stream>>>(pjwb, U5, opbeff, projw, projb, W5, bias2);

    // x = ctx . W[lang]^T + bias2 + hidden -> d_out (f32).  128^2 tiles.
    k_xfused<<<dim3(48, 6), 256, 0, stream>>>(rA, W5, bias2, lang, hidden, out);
    // layernorm in place (4 rows per 256-thr block)
    k_ln<<<(unsigned)(Bn * Sn / 4), 256, 0, stream>>>(out, ln_g, ln_b);
}